// Round 10
// baseline (95.467 us; speedup 1.0000x reference)
//
#include <hip/hip_runtime.h>

// QuantizedConv2d int8 3x3, N=64, Cin=Cout=128, 56x56, pad=1 (value = input zp),
// int32 accum, per-channel requant. Harness widens integer arrays to int32
// (inputs AND output buffer).
//
// R10: wave-per-N-tile decomposition. Each of 4 waves owns one 32-cout tile
// and holds its FULL-K B operand in 144 VGPRs (loaded once from L2). Wave
// loops over the block's 7 M-tiles (224 px): 36 ds_read_b128 (A) + 36 MFMA +
// epilogue per tile, acc only 16-32 regs, no barriers after x-staging, no B
// re-reads, no padded 8th M-tile. Odd tail tile splits K over two accs
// (exact int32). repack_x / pack_w2 / staging / swizzle algebra unchanged
// (verified R7-R9).

#define CIN  128
#define COUT 128
#define HW   56
#define NPIX (HW * HW)
#define ROWS  4
#define QCOLS 58
#define XROW  (QCOLS * CIN)          // 7424 B per padded row
#define XP_OFF 147456                // xp starts after wp2 in d_ws
#define XP_ROWS (64 * QCOLS)         // 3712

typedef int v4i  __attribute__((ext_vector_type(4)));
typedef int v16i __attribute__((ext_vector_type(16)));

__device__ __forceinline__ void gl16(const void* g, void* l) {
    __builtin_amdgcn_global_load_lds(
        (const __attribute__((address_space(1))) unsigned*)g,
        (__attribute__((address_space(3))) unsigned*)l, 16, 0, 0);
}

// ---- pack weights, swizzled (unchanged, verified) ----
// step = t*4+cb; in-chunk granule g = cout*2+(dw>>2); gs = g ^ ((g>>3)&7);
// chunk dword = gs*4 + (dw&3). byte b of dword dw -> ci = cb*32+dw*4+b, tap t.
__global__ __launch_bounds__(256) void pack_w2(const int* __restrict__ w_g,
                                               unsigned* __restrict__ wp2) {
    int i = blockIdx.x * 256 + threadIdx.x;
    if (i >= 36 * 128 * 8) return;
    int dw   = i & 7;
    int cout = (i >> 3) & 127;
    int step = i >> 10;
    int t  = step >> 2;
    int cb = step & 3;
    unsigned d = 0;
#pragma unroll
    for (int b = 0; b < 4; ++b) {
        int ci = cb * 32 + dw * 4 + b;
        int v = w_g[(cout * CIN + ci) * 9 + t];
        d |= (unsigned)(v & 0xFF) << (8 * b);
    }
    int g  = (cout << 1) | (dw >> 2);
    int gs = g ^ ((g >> 3) & 7);
    wp2[step * 1024 + gs * 4 + (dw & 3)] = d;
}

// ---- repack x: LDS transpose (unchanged, verified) ----
#define LSTR 57
__global__ __launch_bounds__(256) void repack_x(const int* __restrict__ x_g,
                                                unsigned char* __restrict__ xp,
                                                const int* __restrict__ zp_in_p) {
    __shared__ int lx[CIN * LSTR];
    const int blk = blockIdx.x;          // n*58 + hp
    const int n  = blk / QCOLS;
    const int hp = blk % QCOLS;
    const int tid = threadIdx.x;
    const unsigned zpd = (unsigned)((*zp_in_p) & 0xFF) * 0x01010101u;
    unsigned* row = (unsigned*)(xp + (size_t)blk * XROW);

    if (hp == 0 || hp == QCOLS - 1) {
#pragma unroll
        for (int it = 0; it < 8; ++it) {
            int d = it * 256 + tid;
            if (d < QCOLS * 32) row[d] = zpd;
        }
        return;
    }
    const int h = hp - 1;
    const int* xrow = x_g + (n * CIN * HW + h) * HW;
#pragma unroll
    for (int it = 0; it < 7; ++it) {
        int idx = it * 256 + tid;
        int ci  = idx / 14;
        int w4  = (idx - ci * 14) * 4;
        v4i L = *(const v4i*)(xrow + ci * NPIX + w4);
        int* ld = &lx[ci * LSTR + w4];
        ld[0] = L[0]; ld[1] = L[1]; ld[2] = L[2]; ld[3] = L[3];
    }
    __syncthreads();
#pragma unroll
    for (int it = 0; it < 8; ++it) {
        int d = it * 256 + tid;
        if (d < QCOLS * 32) {
            int wp  = d >> 5;
            int ci4 = d & 31;
            unsigned v = zpd;
            if (wp >= 1 && wp <= HW) {
                const int* lb = &lx[ci4 * 4 * LSTR + (wp - 1)];
                v = (unsigned)(lb[0] & 0xFF) |
                    ((unsigned)(lb[LSTR] & 0xFF) << 8) |
                    ((unsigned)(lb[2 * LSTR] & 0xFF) << 16) |
                    ((unsigned)(lb[3 * LSTR] & 0xFF) << 24);
            }
            row[d] = v;
        }
    }
}

// ---- conv: wave-per-N-tile, full-K B in registers ----
__global__ __launch_bounds__(256, 2) void conv_mfma(
    const unsigned char* __restrict__ xp, const unsigned char* __restrict__ wp2b,
    const int* __restrict__ bias, const float* __restrict__ in_s,
    const float* __restrict__ w_s, const float* __restrict__ out_s,
    const int* __restrict__ zp_out_p, int* __restrict__ out) {
    __shared__ unsigned char xsb[45056];     // 44 x 1024B (348 rows used)
    __shared__ float scs[COUT];
    __shared__ int   bis[COUT];

    const int n   = blockIdx.x / 14;
    const int ho0 = (blockIdx.x % 14) * ROWS;
    const int tid    = threadIdx.x;
    const int lane   = tid & 63;
    const int wave   = tid >> 6;     // = N-tile (cout block wave*32)
    const int lane31 = lane & 31;
    const int hi     = lane >> 5;
    const int hi4    = hi * 4;

    if (tid < COUT) {
        scs[tid] = ((*in_s) / (*out_s)) * w_s[tid];
        bis[tid] = bias[tid];
    }

    // ---- stage x window: 6 padded rows = 44544 contiguous bytes ----
    const unsigned char* win = xp + (size_t)(n * QCOLS + ho0) * XROW;
    const int qrel = lane >> 3;
    const int lof  = (qrel * 8 + ((lane & 7) ^ qrel)) * 16;
    for (int i = wave; i < 44; i += 4) {
        int off = i * 1024 + lof;
        if (i == 43 && qrel >= 4) off = 0;           // rows 348+ unused
        gl16(win + off, xsb + i * 1024);
    }

    // ---- load this wave's full-K B: 36 x dwordx4 = 144 VGPRs ----
    const int gg  = wave * 64 + lane31 * 2 + hi;
    const int boff = (gg ^ ((gg >> 3) & 7)) * 16;
    v4i breg[36];
#pragma unroll
    for (int s = 0; s < 36; ++s)
        breg[s] = *(const v4i*)(wp2b + s * 4096 + boff);

    __syncthreads();   // x staged (drains all VMEM incl. breg)

    const unsigned* xs = (const unsigned*)xsb;
    const float zpo = (float)(*zp_out_p);

#define ASTEP(ACC, QB, T, CB)                                                \
    {                                                                        \
        const int kr = ((T) * 11) >> 5;                                      \
        const int dq = kr * QCOLS + ((T) - 3 * kr);                          \
        const int q = (QB) + dq;                                             \
        const int sx = (q & 7) << 2;                                         \
        v4i a = *(const v4i*)&xs[q * 32 + (((CB) * 8 + hi4) ^ sx)];          \
        ACC = __builtin_amdgcn_mfma_i32_32x32x32_i8(breg[(T) * 4 + (CB)], a, \
                                                    ACC, 0, 0, 0);           \
    }

#define EPI(ACC, MT)                                                         \
    {                                                                        \
        const int px = (MT) * 32 + lane31;                                   \
        int* ob = out + n * COUT * NPIX + ho0 * HW + px;                     \
        _Pragma("unroll")                                                    \
        for (int reg = 0; reg < 16; ++reg) {                                 \
            const int co = wave * 32 + (reg & 3) + 8 * (reg >> 2) + hi4;     \
            float f = fmaf((float)(ACC[reg] + bis[co]), scs[co], zpo);       \
            f = rintf(f);                                                    \
            f = fminf(fmaxf(f, -128.0f), 127.0f);                            \
            ob[co * NPIX] = (int)f;                                          \
        }                                                                    \
    }

#define PAIR(MT0, MT1)                                                       \
    {                                                                        \
        const int px0 = (MT0) * 32 + lane31;                                 \
        const int px1 = (MT1) * 32 + lane31;                                 \
        const int qb0 = (px0 / HW) * QCOLS + (px0 % HW);                     \
        const int qb1 = (px1 / HW) * QCOLS + (px1 % HW);                     \
        v16i acc0 = (v16i)0, acc1 = (v16i)0;                                 \
        _Pragma("unroll")                                                    \
        for (int t = 0; t < 9; ++t) {                                        \
            _Pragma("unroll")                                                \
            for (int cb = 0; cb < 4; ++cb) {                                 \
                ASTEP(acc0, qb0, t, cb);                                     \
                ASTEP(acc1, qb1, t, cb);                                     \
            }                                                                \
        }                                                                    \
        EPI(acc0, MT0);                                                      \
        EPI(acc1, MT1);                                                      \
    }

    PAIR(0, 1);
    PAIR(2, 3);
    PAIR(4, 5);
    // tail M-tile 6: split K across two accs (exact int32 sum)
    {
        const int px0 = 6 * 32 + lane31;
        const int qb0 = (px0 / HW) * QCOLS + (px0 % HW);
        v16i acc0 = (v16i)0, acc1 = (v16i)0;
#pragma unroll
        for (int t = 0; t < 4; ++t)
#pragma unroll
            for (int cb = 0; cb < 4; ++cb) ASTEP(acc0, qb0, t, cb);
        ASTEP(acc0, qb0, 4, 0);
        ASTEP(acc0, qb0, 4, 1);
        ASTEP(acc1, qb0, 4, 2);
        ASTEP(acc1, qb0, 4, 3);
#pragma unroll
        for (int t = 5; t < 9; ++t)
#pragma unroll
            for (int cb = 0; cb < 4; ++cb) ASTEP(acc1, qb0, t, cb);
#pragma unroll
        for (int r = 0; r < 16; ++r) acc0[r] += acc1[r];
        EPI(acc0, 6);
    }
#undef PAIR
#undef EPI
#undef ASTEP
}

extern "C" void kernel_launch(void* const* d_in, const int* in_sizes, int n_in,
                              void* d_out, int out_size, void* d_ws, size_t ws_size,
                              hipStream_t stream) {
    const int* x_g      = (const int*)d_in[0];
    const int* w_g      = (const int*)d_in[1];
    const int* bias     = (const int*)d_in[2];
    const float* in_s   = (const float*)d_in[3];
    const float* w_s    = (const float*)d_in[4];
    const float* out_s  = (const float*)d_in[5];
    const int* zp_in_p  = (const int*)d_in[6];
    const int* zp_out_p = (const int*)d_in[7];
    int* outp = (int*)d_out;
    unsigned* wp2 = (unsigned*)d_ws;                           // 147456 B
    unsigned char* xpp = (unsigned char*)d_ws + XP_OFF;        // 27,557,888 B

    pack_w2<<<(36 * 128 * 8 + 255) / 256, 256, 0, stream>>>(w_g, wp2);
    repack_x<<<XP_ROWS, 256, 0, stream>>>(x_g, xpp, zp_in_p);

    const int nblocks = 64 * (HW / ROWS);   // 896
    conv_mfma<<<nblocks, 256, 0, stream>>>(xpp, (const unsigned char*)wp2, bias,
                                           in_s, w_s, out_s, zp_out_p, outp);
}